// Round 1
// baseline (409.263 us; speedup 1.0000x reference)
//
#include <hip/hip_runtime.h>
#include <hip/hip_fp16.h>
#include <math.h>

typedef __attribute__((ext_vector_type(8))) _Float16 half8;
typedef __attribute__((ext_vector_type(4))) _Float16 half4;
typedef __attribute__((ext_vector_type(4))) float f32x4;

#define HQ 16
#define HK 4
#define DH 64
#define NB 2
#define SEQ 2048
#define EDIM 1024
#define KD 1024

// ---------------- prep: convert x to f16 ----------------
__global__ __launch_bounds__(256) void cvt_x_kernel(const float* __restrict__ x,
                                                    _Float16* __restrict__ xh, int n4) {
  int i = blockIdx.x * 256 + threadIdx.x;
  if (i >= n4) return;
  float4 v = ((const float4*)x)[i];
  half4 h;
  h[0] = (_Float16)v.x; h[1] = (_Float16)v.y; h[2] = (_Float16)v.z; h[3] = (_Float16)v.w;
  *(half4*)(xh + (size_t)i * 4) = h;
}

// ---------------- prep: W [K][N] f32 -> WT [N][K] f16 ----------------
__global__ __launch_bounds__(256) void transpose_w_kernel(const float* __restrict__ W,
                                                          _Float16* __restrict__ WT,
                                                          int N, int row_off) {
  __shared__ float t[64][65];
  int n0 = blockIdx.x * 64, k0 = blockIdx.y * 64;
  int tid = threadIdx.x;
#pragma unroll
  for (int p = 0; p < 4; ++p) {
    int idx = tid + p * 256;
    int r = idx >> 4;      // k row 0..63
    int c4 = idx & 15;     // float4 col
    float4 v = *(const float4*)(W + (size_t)(k0 + r) * N + n0 + c4 * 4);
    t[r][c4 * 4 + 0] = v.x; t[r][c4 * 4 + 1] = v.y;
    t[r][c4 * 4 + 2] = v.z; t[r][c4 * 4 + 3] = v.w;
  }
  __syncthreads();
#pragma unroll
  for (int p = 0; p < 4; ++p) {
    int idx = tid + p * 256;
    int n = idx >> 4;
    int k4 = idx & 15;
    half4 h;
    h[0] = (_Float16)t[k4 * 4 + 0][n]; h[1] = (_Float16)t[k4 * 4 + 1][n];
    h[2] = (_Float16)t[k4 * 4 + 2][n]; h[3] = (_Float16)t[k4 * 4 + 3][n];
    *(half4*)(WT + (size_t)(row_off + n0 + n) * KD + k0 + k4 * 4) = h;
  }
}

// swizzle: XOR bits 4-6 of the byte offset with row&7 (row stride 128B tiles)
#define SWZ(r, kb) ((kb) ^ (((r) & 7) << 4))

// ---------------- K1: fused QKV GEMM + RoPE ----------------
// C[4096][1536] = xh[4096][1024] @ W; cols 0-1023 -> q, 1024-1279 -> k, 1280-1535 -> v
__global__ __launch_bounds__(256) void gemm_qkv_rope(
    const _Float16* __restrict__ xh, const _Float16* __restrict__ WT,
    const int* __restrict__ q_pos,
    _Float16* __restrict__ qh, _Float16* __restrict__ kh, _Float16* __restrict__ vh) {
  __shared__ char As[128 * 64 * 2];
  __shared__ char Bs[128 * 64 * 2];
  int tid = threadIdx.x, lane = tid & 63, wid = tid >> 6;
  int wr = wid >> 1, wc = wid & 1;
  int bm = blockIdx.x, bn = blockIdx.y;

  const _Float16* Ag = xh + (size_t)bm * 128 * KD;
  const _Float16* Bg = WT + (size_t)bn * 128 * KD;

  f32x4 acc[4][4] = {};

  for (int kt = 0; kt < KD / 64; ++kt) {
#pragma unroll
    for (int p = 0; p < 4; ++p) {
      int idx = tid + p * 256;
      int r = idx >> 3, k8 = idx & 7;
      half8 va = *(const half8*)(Ag + (size_t)r * KD + kt * 64 + k8 * 8);
      *(half8*)(As + r * 128 + SWZ(r, k8 * 16)) = va;
      half8 vb = *(const half8*)(Bg + (size_t)r * KD + kt * 64 + k8 * 8);
      *(half8*)(Bs + r * 128 + SWZ(r, k8 * 16)) = vb;
    }
    __syncthreads();
#pragma unroll
    for (int kk = 0; kk < 2; ++kk) {
      int kb = kk * 64 + (lane >> 4) * 16;
      half8 af[4], bf[4];
#pragma unroll
      for (int mf = 0; mf < 4; ++mf) {
        int r = wr * 64 + mf * 16 + (lane & 15);
        af[mf] = *(const half8*)(As + r * 128 + SWZ(r, kb));
      }
#pragma unroll
      for (int nf = 0; nf < 4; ++nf) {
        int r = wc * 64 + nf * 16 + (lane & 15);
        bf[nf] = *(const half8*)(Bs + r * 128 + SWZ(r, kb));
      }
#pragma unroll
      for (int mf = 0; mf < 4; ++mf)
#pragma unroll
        for (int nf = 0; nf < 4; ++nf)
          acc[mf][nf] = __builtin_amdgcn_mfma_f32_16x16x32_f16(af[mf], bf[nf], acc[mf][nf], 0, 0, 0);
    }
    __syncthreads();
  }

  // epilogue: wave covers 64 contiguous cols = exactly one head
  int col0 = bn * 128 + wc * 64;
  int row_base = bm * 128 + wr * 64;
#pragma unroll
  for (int mf = 0; mf < 4; ++mf) {
#pragma unroll
    for (int j = 0; j < 4; ++j) {
      int row = row_base + mf * 16 + (lane >> 4) * 4 + j;
      int b = row >> 11, s = row & (SEQ - 1);
      if (col0 < 1024) {
        int hq = col0 >> 6;
        float pos = (float)q_pos[row];
        size_t base = (((size_t)b * HQ + hq) * SEQ + s) * DH;
#pragma unroll
        for (int nf = 0; nf < 2; ++nf) {
          int d = nf * 16 + (lane & 15);  // 0..31
          float ang = pos * expf((float)d * -0.2878231366242558f); // -ln(10000)/32
          float sn, cs;
          sincosf(ang, &sn, &cs);
          float x1 = acc[mf][nf][j], x2 = acc[mf][nf + 2][j];
          qh[base + d]      = (_Float16)(x1 * cs - x2 * sn);
          qh[base + d + 32] = (_Float16)(x2 * cs + x1 * sn);
        }
      } else if (col0 < 1280) {
        int hk = (col0 - 1024) >> 6;
        float pos = (float)q_pos[row];
        size_t base = (((size_t)b * HK + hk) * SEQ + s) * DH;
#pragma unroll
        for (int nf = 0; nf < 2; ++nf) {
          int d = nf * 16 + (lane & 15);
          float ang = pos * expf((float)d * -0.2878231366242558f);
          float sn, cs;
          sincosf(ang, &sn, &cs);
          float x1 = acc[mf][nf][j], x2 = acc[mf][nf + 2][j];
          kh[base + d]      = (_Float16)(x1 * cs - x2 * sn);
          kh[base + d + 32] = (_Float16)(x2 * cs + x1 * sn);
        }
      } else {
        int hk = (col0 - 1280) >> 6;
        size_t base = (((size_t)b * HK + hk) * SEQ + s) * DH;
#pragma unroll
        for (int nf = 0; nf < 4; ++nf) {
          int d = nf * 16 + (lane & 15);
          vh[base + d] = (_Float16)acc[mf][nf][j];
        }
      }
    }
  }
}

// ---------------- K2: flash attention (scale=1.0) ----------------
// grid: (qt=16, bh=32). block 256 = 4 waves x 32 q-rows. KV tile = 128.
__global__ __launch_bounds__(256) void attn_kernel(
    const _Float16* __restrict__ qh, const _Float16* __restrict__ kh,
    const _Float16* __restrict__ vh, _Float16* __restrict__ oh) {
  __shared__ char Ks[128 * 64 * 2];      // [kv][d] swz, row 128B
  __shared__ char Vs[64 * 128 * 2];      // [d][kv] swz, row 256B
  __shared__ char Ps[4 * 32 * 64 * 2];   // per-wave [32 q][64 kv] swz, row 128B

  int tid = threadIdx.x, lane = tid & 63, wid = tid >> 6;
  int qt = blockIdx.x;
  int bh = blockIdx.y;
  int b = bh >> 4, hq = bh & 15, hk = hq >> 2;

  const _Float16* Qg = qh + (((size_t)b * HQ + hq) * SEQ + qt * 128 + wid * 32) * DH;
  const _Float16* Kg = kh + (((size_t)b * HK + hk) * SEQ) * DH;
  const _Float16* Vg = vh + (((size_t)b * HK + hk) * SEQ) * DH;

  // Q fragments held in registers for the whole block
  half8 qf[2][2];
#pragma unroll
  for (int mf = 0; mf < 2; ++mf)
#pragma unroll
    for (int kk = 0; kk < 2; ++kk)
      qf[mf][kk] = *(const half8*)(Qg + (mf * 16 + (lane & 15)) * DH + kk * 32 + (lane >> 4) * 8);

  f32x4 oacc[2][4] = {};
  float mrow[2][4], lrow[2][4];
#pragma unroll
  for (int mf = 0; mf < 2; ++mf)
#pragma unroll
    for (int j = 0; j < 4; ++j) { mrow[mf][j] = -3e38f; lrow[mf][j] = 0.f; }

  char* Pw = Ps + wid * (32 * 64 * 2);

  for (int kt = 0; kt < SEQ / 128; ++kt) {
    // stage K [128][64] direct; V transposed -> Vs[d][kv]
#pragma unroll
    for (int p = 0; p < 4; ++p) {
      int idx = tid + p * 256;
      int r = idx >> 3, d8 = idx & 7;
      half8 vk = *(const half8*)(Kg + ((size_t)kt * 128 + r) * DH + d8 * 8);
      *(half8*)(Ks + r * 128 + SWZ(r, d8 * 16)) = vk;
      half8 vv = *(const half8*)(Vg + ((size_t)kt * 128 + r) * DH + d8 * 8);
#pragma unroll
      for (int i = 0; i < 8; ++i) {
        int d = d8 * 8 + i;
        *(_Float16*)(Vs + d * 256 + SWZ(d, r * 2)) = vv[i];
      }
    }
    __syncthreads();

    // scores S[32 q][128 kv] = Q K^T
    f32x4 sc[2][8] = {};
#pragma unroll
    for (int nf = 0; nf < 8; ++nf) {
      int r = nf * 16 + (lane & 15);
      half8 kf0 = *(const half8*)(Ks + r * 128 + SWZ(r, (lane >> 4) * 16));
      half8 kf1 = *(const half8*)(Ks + r * 128 + SWZ(r, (lane >> 4) * 16 + 64));
#pragma unroll
      for (int mf = 0; mf < 2; ++mf) {
        sc[mf][nf] = __builtin_amdgcn_mfma_f32_16x16x32_f16(qf[mf][0], kf0, sc[mf][nf], 0, 0, 0);
        sc[mf][nf] = __builtin_amdgcn_mfma_f32_16x16x32_f16(qf[mf][1], kf1, sc[mf][nf], 0, 0, 0);
      }
    }

    // online softmax (rows split across 16-lane groups; reduce over lane&15)
#pragma unroll
    for (int mf = 0; mf < 2; ++mf) {
#pragma unroll
      for (int j = 0; j < 4; ++j) {
        float pm = sc[mf][0][j];
#pragma unroll
        for (int nf = 1; nf < 8; ++nf) pm = fmaxf(pm, sc[mf][nf][j]);
        pm = fmaxf(pm, __shfl_xor(pm, 1, 64));
        pm = fmaxf(pm, __shfl_xor(pm, 2, 64));
        pm = fmaxf(pm, __shfl_xor(pm, 4, 64));
        pm = fmaxf(pm, __shfl_xor(pm, 8, 64));
        float mnew = fmaxf(mrow[mf][j], pm);
        float alpha = __expf(mrow[mf][j] - mnew);
        mrow[mf][j] = mnew;
        float psum = 0.f;
#pragma unroll
        for (int nf = 0; nf < 8; ++nf) {
          float pv = __expf(sc[mf][nf][j] - mnew);
          sc[mf][nf][j] = pv;
          psum += pv;
        }
        psum += __shfl_xor(psum, 1, 64);
        psum += __shfl_xor(psum, 2, 64);
        psum += __shfl_xor(psum, 4, 64);
        psum += __shfl_xor(psum, 8, 64);
        lrow[mf][j] = lrow[mf][j] * alpha + psum;
#pragma unroll
        for (int nf2 = 0; nf2 < 4; ++nf2) oacc[mf][nf2][j] *= alpha;
      }
    }

    // PV: P via per-wave LDS roundtrip, two kv-halves of 64 (reuses Pw; DS ops
    // from one wave execute in program order so h=1 writes can't pass h=0 reads)
#pragma unroll
    for (int h = 0; h < 2; ++h) {
#pragma unroll
      for (int mf = 0; mf < 2; ++mf)
#pragma unroll
        for (int nfl = 0; nfl < 4; ++nfl)
#pragma unroll
          for (int j = 0; j < 4; ++j) {
            int r = mf * 16 + (lane >> 4) * 4 + j;
            int c = nfl * 16 + (lane & 15);
            *(_Float16*)(Pw + r * 128 + SWZ(r, c * 2)) = (_Float16)sc[mf][h * 4 + nfl][j];
          }
#pragma unroll
      for (int kf = 0; kf < 2; ++kf) {
        int kb = kf * 64 + (lane >> 4) * 16;
        half8 pa[2], vb[4];
#pragma unroll
        for (int mf = 0; mf < 2; ++mf) {
          int r = mf * 16 + (lane & 15);
          pa[mf] = *(const half8*)(Pw + r * 128 + SWZ(r, kb));
        }
        int kvb = (h * 2 + kf) * 64 + (lane >> 4) * 16;
#pragma unroll
        for (int nf2 = 0; nf2 < 4; ++nf2) {
          int dd = nf2 * 16 + (lane & 15);
          vb[nf2] = *(const half8*)(Vs + dd * 256 + SWZ(dd, kvb));
        }
#pragma unroll
        for (int mf = 0; mf < 2; ++mf)
#pragma unroll
          for (int nf2 = 0; nf2 < 4; ++nf2)
            oacc[mf][nf2] = __builtin_amdgcn_mfma_f32_16x16x32_f16(pa[mf], vb[nf2], oacc[mf][nf2], 0, 0, 0);
      }
    }
    __syncthreads();
  }

  // normalize + write [B][S][HQ*DH]
  int s0 = qt * 128 + wid * 32;
#pragma unroll
  for (int mf = 0; mf < 2; ++mf) {
#pragma unroll
    for (int j = 0; j < 4; ++j) {
      int s = s0 + mf * 16 + (lane >> 4) * 4 + j;
      float invl = 1.f / lrow[mf][j];
      size_t base = ((size_t)b * SEQ + s) * 1024 + hq * 64;
#pragma unroll
      for (int nf2 = 0; nf2 < 4; ++nf2) {
        int dd = nf2 * 16 + (lane & 15);
        oh[base + dd] = (_Float16)(oacc[mf][nf2][j] * invl);
      }
    }
  }
}

// ---------------- K3: output projection, fp32 out ----------------
__global__ __launch_bounds__(256) void gemm_out(
    const _Float16* __restrict__ ah, const _Float16* __restrict__ WoT,
    float* __restrict__ out) {
  __shared__ char As[128 * 64 * 2];
  __shared__ char Bs[128 * 64 * 2];
  int tid = threadIdx.x, lane = tid & 63, wid = tid >> 6;
  int wr = wid >> 1, wc = wid & 1;
  int bm = blockIdx.x, bn = blockIdx.y;
  const _Float16* Ag = ah + (size_t)bm * 128 * KD;
  const _Float16* Bg = WoT + (size_t)bn * 128 * KD;
  f32x4 acc[4][4] = {};

  for (int kt = 0; kt < KD / 64; ++kt) {
#pragma unroll
    for (int p = 0; p < 4; ++p) {
      int idx = tid + p * 256;
      int r = idx >> 3, k8 = idx & 7;
      half8 va = *(const half8*)(Ag + (size_t)r * KD + kt * 64 + k8 * 8);
      *(half8*)(As + r * 128 + SWZ(r, k8 * 16)) = va;
      half8 vb = *(const half8*)(Bg + (size_t)r * KD + kt * 64 + k8 * 8);
      *(half8*)(Bs + r * 128 + SWZ(r, k8 * 16)) = vb;
    }
    __syncthreads();
#pragma unroll
    for (int kk = 0; kk < 2; ++kk) {
      int kb = kk * 64 + (lane >> 4) * 16;
      half8 af[4], bf[4];
#pragma unroll
      for (int mf = 0; mf < 4; ++mf) {
        int r = wr * 64 + mf * 16 + (lane & 15);
        af[mf] = *(const half8*)(As + r * 128 + SWZ(r, kb));
      }
#pragma unroll
      for (int nf = 0; nf < 4; ++nf) {
        int r = wc * 64 + nf * 16 + (lane & 15);
        bf[nf] = *(const half8*)(Bs + r * 128 + SWZ(r, kb));
      }
#pragma unroll
      for (int mf = 0; mf < 4; ++mf)
#pragma unroll
        for (int nf = 0; nf < 4; ++nf)
          acc[mf][nf] = __builtin_amdgcn_mfma_f32_16x16x32_f16(af[mf], bf[nf], acc[mf][nf], 0, 0, 0);
    }
    __syncthreads();
  }

  int row0 = bm * 128 + wr * 64, col0 = bn * 128 + wc * 64;
#pragma unroll
  for (int mf = 0; mf < 4; ++mf)
#pragma unroll
    for (int j = 0; j < 4; ++j) {
      int row = row0 + mf * 16 + (lane >> 4) * 4 + j;
#pragma unroll
      for (int nf = 0; nf < 4; ++nf)
        out[(size_t)row * 1024 + col0 + nf * 16 + (lane & 15)] = acc[mf][nf][j];
    }
}

// ---------------- launch ----------------
extern "C" void kernel_launch(void* const* d_in, const int* in_sizes, int n_in,
                              void* d_out, int out_size, void* d_ws, size_t ws_size,
                              hipStream_t stream) {
  const float* x  = (const float*)d_in[0];
  const int* qpos = (const int*)d_in[1];
  const float* Wq = (const float*)d_in[2];
  const float* Wk = (const float*)d_in[3];
  const float* Wv = (const float*)d_in[4];
  const float* Wo = (const float*)d_in[5];
  float* out = (float*)d_out;

  char* ws = (char*)d_ws;
  _Float16* xh  = (_Float16*)(ws);                 // 8 MB  [4096][1024]
  _Float16* WT  = (_Float16*)(ws + 8388608);       // 3 MB  [1536][1024] (q,k,v stacked)
  _Float16* WoT = (_Float16*)(ws + 11534336);      // 2 MB  [1024][1024]
  _Float16* qhp = (_Float16*)(ws + 13631488);      // 8 MB  [B][HQ][S][D]
  _Float16* khp = (_Float16*)(ws + 22020096);      // 2 MB  [B][HK][S][D]
  _Float16* vhp = (_Float16*)(ws + 24117248);      // 2 MB  [B][HK][S][D]
  _Float16* ohp = (_Float16*)(ws + 26214400);      // 8 MB  [4096][1024]

  cvt_x_kernel<<<4096, 256, 0, stream>>>(x, xh, 1048576);
  transpose_w_kernel<<<dim3(16, 16), 256, 0, stream>>>(Wq, WT, 1024, 0);
  transpose_w_kernel<<<dim3(4, 16), 256, 0, stream>>>(Wk, WT, 256, 1024);
  transpose_w_kernel<<<dim3(4, 16), 256, 0, stream>>>(Wv, WT, 256, 1280);
  transpose_w_kernel<<<dim3(16, 16), 256, 0, stream>>>(Wo, WoT, 1024, 0);
  gemm_qkv_rope<<<dim3(32, 12), 256, 0, stream>>>(xh, WT, qpos, qhp, khp, vhp);
  attn_kernel<<<dim3(16, 32), 256, 0, stream>>>(qhp, khp, vhp, ohp);
  gemm_out<<<dim3(32, 8), 256, 0, stream>>>(ohp, WoT, out);
}

// Round 2
// 212.542 us; speedup vs baseline: 1.9256x; 1.9256x over previous
//
#include <hip/hip_runtime.h>
#include <hip/hip_fp16.h>
#include <math.h>

typedef __attribute__((ext_vector_type(8))) _Float16 half8;
typedef __attribute__((ext_vector_type(4))) _Float16 half4;
typedef __attribute__((ext_vector_type(4))) float f32x4;

#define HQ 16
#define HK 4
#define DH 64
#define NB 2
#define SEQ 2048
#define EDIM 1024
#define KD 1024

// ---------------- prep: convert x to f16 ----------------
__global__ __launch_bounds__(256) void cvt_x_kernel(const float* __restrict__ x,
                                                    _Float16* __restrict__ xh, int n4) {
  int i = blockIdx.x * 256 + threadIdx.x;
  if (i >= n4) return;
  float4 v = ((const float4*)x)[i];
  half4 h;
  h[0] = (_Float16)v.x; h[1] = (_Float16)v.y; h[2] = (_Float16)v.z; h[3] = (_Float16)v.w;
  *(half4*)(xh + (size_t)i * 4) = h;
}

// ---------------- prep: RoPE sin/cos table [4096 rows][32 freqs] ----------------
__global__ __launch_bounds__(256) void rope_tab_kernel(const int* __restrict__ qpos,
                                                       float2* __restrict__ tab) {
  int i = blockIdx.x * 256 + threadIdx.x;   // 0 .. 4096*32-1
  int row = i >> 5, d = i & 31;
  float ang = (float)qpos[row] * expf((float)d * -0.2878231366242558f); // -ln(10000)/32
  float sn, cs;
  sincosf(ang, &sn, &cs);
  tab[i] = make_float2(sn, cs);
}

// ---------------- prep: W [K][N] f32 -> WT [N][K] f16 ----------------
__global__ __launch_bounds__(256) void transpose_w_kernel(const float* __restrict__ W,
                                                          _Float16* __restrict__ WT,
                                                          int N, int row_off) {
  __shared__ float t[64][65];
  int n0 = blockIdx.x * 64, k0 = blockIdx.y * 64;
  int tid = threadIdx.x;
#pragma unroll
  for (int p = 0; p < 4; ++p) {
    int idx = tid + p * 256;
    int r = idx >> 4;      // k row 0..63
    int c4 = idx & 15;     // float4 col
    float4 v = *(const float4*)(W + (size_t)(k0 + r) * N + n0 + c4 * 4);
    t[r][c4 * 4 + 0] = v.x; t[r][c4 * 4 + 1] = v.y;
    t[r][c4 * 4 + 2] = v.z; t[r][c4 * 4 + 3] = v.w;
  }
  __syncthreads();
#pragma unroll
  for (int p = 0; p < 4; ++p) {
    int idx = tid + p * 256;
    int n = idx >> 4;
    int k4 = idx & 15;
    half4 h;
    h[0] = (_Float16)t[k4 * 4 + 0][n]; h[1] = (_Float16)t[k4 * 4 + 1][n];
    h[2] = (_Float16)t[k4 * 4 + 2][n]; h[3] = (_Float16)t[k4 * 4 + 3][n];
    *(half4*)(WT + (size_t)(row_off + n0 + n) * KD + k0 + k4 * 4) = h;
  }
}

// swizzle: XOR bits 4-6 of the byte offset with row&7 (row stride 128B tiles)
#define SWZ(r, kb) ((kb) ^ (((r) & 7) << 4))

// ---------------- K1: fused QKV GEMM + RoPE (table-driven) ----------------
// C[4096][1536] = xh[4096][1024] @ W; cols 0-1023 -> q, 1024-1279 -> k, 1280-1535 -> v
__global__ __launch_bounds__(256) void gemm_qkv_rope(
    const _Float16* __restrict__ xh, const _Float16* __restrict__ WT,
    const float2* __restrict__ rtab,
    _Float16* __restrict__ qh, _Float16* __restrict__ kh, _Float16* __restrict__ vh) {
  __shared__ char As[128 * 64 * 2];
  __shared__ char Bs[128 * 64 * 2];
  int tid = threadIdx.x, lane = tid & 63, wid = tid >> 6;
  int wr = wid >> 1, wc = wid & 1;
  int bm = blockIdx.x, bn = blockIdx.y;

  const _Float16* Ag = xh + (size_t)bm * 128 * KD;
  const _Float16* Bg = WT + (size_t)bn * 128 * KD;

  f32x4 acc[4][4] = {};

  for (int kt = 0; kt < KD / 64; ++kt) {
#pragma unroll
    for (int p = 0; p < 4; ++p) {
      int idx = tid + p * 256;
      int r = idx >> 3, k8 = idx & 7;
      half8 va = *(const half8*)(Ag + (size_t)r * KD + kt * 64 + k8 * 8);
      *(half8*)(As + r * 128 + SWZ(r, k8 * 16)) = va;
      half8 vb = *(const half8*)(Bg + (size_t)r * KD + kt * 64 + k8 * 8);
      *(half8*)(Bs + r * 128 + SWZ(r, k8 * 16)) = vb;
    }
    __syncthreads();
#pragma unroll
    for (int kk = 0; kk < 2; ++kk) {
      int kb = kk * 64 + (lane >> 4) * 16;
      half8 af[4], bf[4];
#pragma unroll
      for (int mf = 0; mf < 4; ++mf) {
        int r = wr * 64 + mf * 16 + (lane & 15);
        af[mf] = *(const half8*)(As + r * 128 + SWZ(r, kb));
      }
#pragma unroll
      for (int nf = 0; nf < 4; ++nf) {
        int r = wc * 64 + nf * 16 + (lane & 15);
        bf[nf] = *(const half8*)(Bs + r * 128 + SWZ(r, kb));
      }
#pragma unroll
      for (int mf = 0; mf < 4; ++mf)
#pragma unroll
        for (int nf = 0; nf < 4; ++nf)
          acc[mf][nf] = __builtin_amdgcn_mfma_f32_16x16x32_f16(af[mf], bf[nf], acc[mf][nf], 0, 0, 0);
    }
    __syncthreads();
  }

  // epilogue: wave covers 64 contiguous cols = exactly one head
  int col0 = bn * 128 + wc * 64;
  int row_base = bm * 128 + wr * 64;
#pragma unroll
  for (int mf = 0; mf < 4; ++mf) {
#pragma unroll
    for (int j = 0; j < 4; ++j) {
      int row = row_base + mf * 16 + (lane >> 4) * 4 + j;
      int b = row >> 11, s = row & (SEQ - 1);
      if (col0 < 1024) {
        int hq = col0 >> 6;
        size_t base = (((size_t)b * HQ + hq) * SEQ + s) * DH;
#pragma unroll
        for (int nf = 0; nf < 2; ++nf) {
          int d = nf * 16 + (lane & 15);  // 0..31
          float2 scv = rtab[row * 32 + d];
          float x1 = acc[mf][nf][j], x2 = acc[mf][nf + 2][j];
          qh[base + d]      = (_Float16)(x1 * scv.y - x2 * scv.x);
          qh[base + d + 32] = (_Float16)(x2 * scv.y + x1 * scv.x);
        }
      } else if (col0 < 1280) {
        int hk = (col0 - 1024) >> 6;
        size_t base = (((size_t)b * HK + hk) * SEQ + s) * DH;
#pragma unroll
        for (int nf = 0; nf < 2; ++nf) {
          int d = nf * 16 + (lane & 15);
          float2 scv = rtab[row * 32 + d];
          float x1 = acc[mf][nf][j], x2 = acc[mf][nf + 2][j];
          kh[base + d]      = (_Float16)(x1 * scv.y - x2 * scv.x);
          kh[base + d + 32] = (_Float16)(x2 * scv.y + x1 * scv.x);
        }
      } else {
        int hk = (col0 - 1280) >> 6;
        size_t base = (((size_t)b * HK + hk) * SEQ + s) * DH;
#pragma unroll
        for (int nf = 0; nf < 4; ++nf) {
          int d = nf * 16 + (lane & 15);
          vh[base + d] = (_Float16)acc[mf][nf][j];
        }
      }
    }
  }
}

// ---------------- K2: flash attention (scale=1.0) ----------------
// grid: (qt=16, bh=32). block 256 = 4 waves x 32 q-rows. KV tile = 128.
__global__ __launch_bounds__(256) void attn_kernel(
    const _Float16* __restrict__ qh, const _Float16* __restrict__ kh,
    const _Float16* __restrict__ vh, _Float16* __restrict__ oh) {
  __shared__ char Ks[128 * 64 * 2];      // [kv][d] swz, row 128B
  __shared__ char Vs[64 * 128 * 2];      // [d][kv] swz, row 256B
  __shared__ char Ps[4 * 32 * 64 * 2];   // per-wave [32 q][64 kv] swz, row 128B

  int tid = threadIdx.x, lane = tid & 63, wid = tid >> 6;
  int qt = blockIdx.x;
  int bh = blockIdx.y;
  int b = bh >> 4, hq = bh & 15, hk = hq >> 2;

  const _Float16* Qg = qh + (((size_t)b * HQ + hq) * SEQ + qt * 128 + wid * 32) * DH;
  const _Float16* Kg = kh + (((size_t)b * HK + hk) * SEQ) * DH;
  const _Float16* Vg = vh + (((size_t)b * HK + hk) * SEQ) * DH;

  // Q fragments held in registers for the whole block
  half8 qf[2][2];
#pragma unroll
  for (int mf = 0; mf < 2; ++mf)
#pragma unroll
    for (int kk = 0; kk < 2; ++kk)
      qf[mf][kk] = *(const half8*)(Qg + (mf * 16 + (lane & 15)) * DH + kk * 32 + (lane >> 4) * 8);

  f32x4 oacc[2][4] = {};
  float mrow[2][4], lrow[2][4];
#pragma unroll
  for (int mf = 0; mf < 2; ++mf)
#pragma unroll
    for (int j = 0; j < 4; ++j) { mrow[mf][j] = -3e38f; lrow[mf][j] = 0.f; }

  char* Pw = Ps + wid * (32 * 64 * 2);

  for (int kt = 0; kt < SEQ / 128; ++kt) {
    // stage K [128][64] direct; V transposed -> Vs[d][kv]
#pragma unroll
    for (int p = 0; p < 4; ++p) {
      int idx = tid + p * 256;
      int r = idx >> 3, d8 = idx & 7;
      half8 vk = *(const half8*)(Kg + ((size_t)kt * 128 + r) * DH + d8 * 8);
      *(half8*)(Ks + r * 128 + SWZ(r, d8 * 16)) = vk;
      half8 vv = *(const half8*)(Vg + ((size_t)kt * 128 + r) * DH + d8 * 8);
#pragma unroll
      for (int i = 0; i < 8; ++i) {
        int d = d8 * 8 + i;
        *(_Float16*)(Vs + d * 256 + SWZ(d, r * 2)) = vv[i];
      }
    }
    __syncthreads();

    // scores S[32 q][128 kv] = Q K^T
    f32x4 sc[2][8] = {};
#pragma unroll
    for (int nf = 0; nf < 8; ++nf) {
      int r = nf * 16 + (lane & 15);
      half8 kf0 = *(const half8*)(Ks + r * 128 + SWZ(r, (lane >> 4) * 16));
      half8 kf1 = *(const half8*)(Ks + r * 128 + SWZ(r, (lane >> 4) * 16 + 64));
#pragma unroll
      for (int mf = 0; mf < 2; ++mf) {
        sc[mf][nf] = __builtin_amdgcn_mfma_f32_16x16x32_f16(qf[mf][0], kf0, sc[mf][nf], 0, 0, 0);
        sc[mf][nf] = __builtin_amdgcn_mfma_f32_16x16x32_f16(qf[mf][1], kf1, sc[mf][nf], 0, 0, 0);
      }
    }

    // online softmax (rows split across 16-lane groups; reduce over lane&15)
#pragma unroll
    for (int mf = 0; mf < 2; ++mf) {
#pragma unroll
      for (int j = 0; j < 4; ++j) {
        float pm = sc[mf][0][j];
#pragma unroll
        for (int nf = 1; nf < 8; ++nf) pm = fmaxf(pm, sc[mf][nf][j]);
        pm = fmaxf(pm, __shfl_xor(pm, 1, 64));
        pm = fmaxf(pm, __shfl_xor(pm, 2, 64));
        pm = fmaxf(pm, __shfl_xor(pm, 4, 64));
        pm = fmaxf(pm, __shfl_xor(pm, 8, 64));
        float mnew = fmaxf(mrow[mf][j], pm);
        float alpha = __expf(mrow[mf][j] - mnew);
        mrow[mf][j] = mnew;
        float psum = 0.f;
#pragma unroll
        for (int nf = 0; nf < 8; ++nf) {
          float pv = __expf(sc[mf][nf][j] - mnew);
          sc[mf][nf][j] = pv;
          psum += pv;
        }
        psum += __shfl_xor(psum, 1, 64);
        psum += __shfl_xor(psum, 2, 64);
        psum += __shfl_xor(psum, 4, 64);
        psum += __shfl_xor(psum, 8, 64);
        lrow[mf][j] = lrow[mf][j] * alpha + psum;
#pragma unroll
        for (int nf2 = 0; nf2 < 4; ++nf2) oacc[mf][nf2][j] *= alpha;
      }
    }

    // PV: P via per-wave LDS roundtrip, two kv-halves of 64 (reuses Pw; DS ops
    // from one wave execute in program order so h=1 writes can't pass h=0 reads)
#pragma unroll
    for (int h = 0; h < 2; ++h) {
#pragma unroll
      for (int mf = 0; mf < 2; ++mf)
#pragma unroll
        for (int nfl = 0; nfl < 4; ++nfl)
#pragma unroll
          for (int j = 0; j < 4; ++j) {
            int r = mf * 16 + (lane >> 4) * 4 + j;
            int c = nfl * 16 + (lane & 15);
            *(_Float16*)(Pw + r * 128 + SWZ(r, c * 2)) = (_Float16)sc[mf][h * 4 + nfl][j];
          }
#pragma unroll
      for (int kf = 0; kf < 2; ++kf) {
        int kb = kf * 64 + (lane >> 4) * 16;
        half8 pa[2], vb[4];
#pragma unroll
        for (int mf = 0; mf < 2; ++mf) {
          int r = mf * 16 + (lane & 15);
          pa[mf] = *(const half8*)(Pw + r * 128 + SWZ(r, kb));
        }
        int kvb = (h * 2 + kf) * 64 + (lane >> 4) * 16;
#pragma unroll
        for (int nf2 = 0; nf2 < 4; ++nf2) {
          int dd = nf2 * 16 + (lane & 15);
          vb[nf2] = *(const half8*)(Vs + dd * 256 + SWZ(dd, kvb));
        }
#pragma unroll
        for (int mf = 0; mf < 2; ++mf)
#pragma unroll
          for (int nf2 = 0; nf2 < 4; ++nf2)
            oacc[mf][nf2] = __builtin_amdgcn_mfma_f32_16x16x32_f16(pa[mf], vb[nf2], oacc[mf][nf2], 0, 0, 0);
      }
    }
    __syncthreads();
  }

  // normalize + write [B][S][HQ*DH]
  int s0 = qt * 128 + wid * 32;
#pragma unroll
  for (int mf = 0; mf < 2; ++mf) {
#pragma unroll
    for (int j = 0; j < 4; ++j) {
      int s = s0 + mf * 16 + (lane >> 4) * 4 + j;
      float invl = 1.f / lrow[mf][j];
      size_t base = ((size_t)b * SEQ + s) * 1024 + hq * 64;
#pragma unroll
      for (int nf2 = 0; nf2 < 4; ++nf2) {
        int dd = nf2 * 16 + (lane & 15);
        oh[base + dd] = (_Float16)(oacc[mf][nf2][j] * invl);
      }
    }
  }
}

// ---------------- K3: output projection, fp32 out ----------------
__global__ __launch_bounds__(256) void gemm_out(
    const _Float16* __restrict__ ah, const _Float16* __restrict__ WoT,
    float* __restrict__ out) {
  __shared__ char As[128 * 64 * 2];
  __shared__ char Bs[128 * 64 * 2];
  int tid = threadIdx.x, lane = tid & 63, wid = tid >> 6;
  int wr = wid >> 1, wc = wid & 1;
  int bm = blockIdx.x, bn = blockIdx.y;
  const _Float16* Ag = ah + (size_t)bm * 128 * KD;
  const _Float16* Bg = WoT + (size_t)bn * 128 * KD;
  f32x4 acc[4][4] = {};

  for (int kt = 0; kt < KD / 64; ++kt) {
#pragma unroll
    for (int p = 0; p < 4; ++p) {
      int idx = tid + p * 256;
      int r = idx >> 3, k8 = idx & 7;
      half8 va = *(const half8*)(Ag + (size_t)r * KD + kt * 64 + k8 * 8);
      *(half8*)(As + r * 128 + SWZ(r, k8 * 16)) = va;
      half8 vb = *(const half8*)(Bg + (size_t)r * KD + kt * 64 + k8 * 8);
      *(half8*)(Bs + r * 128 + SWZ(r, k8 * 16)) = vb;
    }
    __syncthreads();
#pragma unroll
    for (int kk = 0; kk < 2; ++kk) {
      int kb = kk * 64 + (lane >> 4) * 16;
      half8 af[4], bf[4];
#pragma unroll
      for (int mf = 0; mf < 4; ++mf) {
        int r = wr * 64 + mf * 16 + (lane & 15);
        af[mf] = *(const half8*)(As + r * 128 + SWZ(r, kb));
      }
#pragma unroll
      for (int nf = 0; nf < 4; ++nf) {
        int r = wc * 64 + nf * 16 + (lane & 15);
        bf[nf] = *(const half8*)(Bs + r * 128 + SWZ(r, kb));
      }
#pragma unroll
      for (int mf = 0; mf < 4; ++mf)
#pragma unroll
        for (int nf = 0; nf < 4; ++nf)
          acc[mf][nf] = __builtin_amdgcn_mfma_f32_16x16x32_f16(af[mf], bf[nf], acc[mf][nf], 0, 0, 0);
    }
    __syncthreads();
  }

  int row0 = bm * 128 + wr * 64, col0 = bn * 128 + wc * 64;
#pragma unroll
  for (int mf = 0; mf < 4; ++mf)
#pragma unroll
    for (int j = 0; j < 4; ++j) {
      int row = row0 + mf * 16 + (lane >> 4) * 4 + j;
#pragma unroll
      for (int nf = 0; nf < 4; ++nf)
        out[(size_t)row * 1024 + col0 + nf * 16 + (lane & 15)] = acc[mf][nf][j];
    }
}

// ---------------- launch ----------------
extern "C" void kernel_launch(void* const* d_in, const int* in_sizes, int n_in,
                              void* d_out, int out_size, void* d_ws, size_t ws_size,
                              hipStream_t stream) {
  const float* x  = (const float*)d_in[0];
  const int* qpos = (const int*)d_in[1];
  const float* Wq = (const float*)d_in[2];
  const float* Wk = (const float*)d_in[3];
  const float* Wv = (const float*)d_in[4];
  const float* Wo = (const float*)d_in[5];
  float* out = (float*)d_out;

  char* ws = (char*)d_ws;
  _Float16* xh  = (_Float16*)(ws);                 // 8 MB  [4096][1024]
  _Float16* WT  = (_Float16*)(ws + 8388608);       // 3 MB  [1536][1024] (q,k,v stacked)
  _Float16* WoT = (_Float16*)(ws + 11534336);      // 2 MB  [1024][1024]
  _Float16* qhp = (_Float16*)(ws + 13631488);      // 8 MB  [B][HQ][S][D]
  _Float16* khp = (_Float16*)(ws + 22020096);      // 2 MB  [B][HK][S][D]
  _Float16* vhp = (_Float16*)(ws + 24117248);      // 2 MB  [B][HK][S][D]
  _Float16* ohp = (_Float16*)(ws + 26214400);      // 8 MB  [4096][1024]
  float2*   rtab = (float2*)(ws + 34603008);       // 1 MB  [4096][32]

  cvt_x_kernel<<<4096, 256, 0, stream>>>(x, xh, 1048576);
  rope_tab_kernel<<<512, 256, 0, stream>>>(qpos, rtab);
  transpose_w_kernel<<<dim3(16, 16), 256, 0, stream>>>(Wq, WT, 1024, 0);
  transpose_w_kernel<<<dim3(4, 16), 256, 0, stream>>>(Wk, WT, 256, 1024);
  transpose_w_kernel<<<dim3(4, 16), 256, 0, stream>>>(Wv, WT, 256, 1280);
  transpose_w_kernel<<<dim3(16, 16), 256, 0, stream>>>(Wo, WoT, 1024, 0);
  gemm_qkv_rope<<<dim3(32, 12), 256, 0, stream>>>(xh, WT, rtab, qhp, khp, vhp);
  attn_kernel<<<dim3(16, 32), 256, 0, stream>>>(qhp, khp, vhp, ohp);
  gemm_out<<<dim3(32, 8), 256, 0, stream>>>(ohp, WoT, out);
}

// Round 3
// 189.582 us; speedup vs baseline: 2.1588x; 1.1211x over previous
//
#include <hip/hip_runtime.h>
#include <hip/hip_fp16.h>
#include <math.h>

typedef __attribute__((ext_vector_type(8))) _Float16 half8;
typedef __attribute__((ext_vector_type(4))) _Float16 half4;
typedef __attribute__((ext_vector_type(4))) float f32x4;

#define HQ 16
#define HK 4
#define DH 64
#define NB 2
#define SEQ 2048
#define EDIM 1024
#define KD 1024

// ---------------- prep: convert x to f16 ----------------
__global__ __launch_bounds__(256) void cvt_x_kernel(const float* __restrict__ x,
                                                    _Float16* __restrict__ xh, int n4) {
  int i = blockIdx.x * 256 + threadIdx.x;
  if (i >= n4) return;
  float4 v = ((const float4*)x)[i];
  half4 h;
  h[0] = (_Float16)v.x; h[1] = (_Float16)v.y; h[2] = (_Float16)v.z; h[3] = (_Float16)v.w;
  *(half4*)(xh + (size_t)i * 4) = h;
}

// ---------------- prep: RoPE sin/cos table [4096 rows][32 freqs] ----------------
__global__ __launch_bounds__(256) void rope_tab_kernel(const int* __restrict__ qpos,
                                                       float2* __restrict__ tab) {
  int i = blockIdx.x * 256 + threadIdx.x;   // 0 .. 4096*32-1
  int row = i >> 5, d = i & 31;
  float ang = (float)qpos[row] * expf((float)d * -0.2878231366242558f); // -ln(10000)/32
  float sn, cs;
  sincosf(ang, &sn, &cs);
  tab[i] = make_float2(sn, cs);
}

// ---------------- prep: W [K][N] f32 -> WT [N][K] f16 ----------------
__global__ __launch_bounds__(256) void transpose_w_kernel(const float* __restrict__ W,
                                                          _Float16* __restrict__ WT,
                                                          int N, int row_off) {
  __shared__ float t[64][65];
  int n0 = blockIdx.x * 64, k0 = blockIdx.y * 64;
  int tid = threadIdx.x;
#pragma unroll
  for (int p = 0; p < 4; ++p) {
    int idx = tid + p * 256;
    int r = idx >> 4;      // k row 0..63
    int c4 = idx & 15;     // float4 col
    float4 v = *(const float4*)(W + (size_t)(k0 + r) * N + n0 + c4 * 4);
    t[r][c4 * 4 + 0] = v.x; t[r][c4 * 4 + 1] = v.y;
    t[r][c4 * 4 + 2] = v.z; t[r][c4 * 4 + 3] = v.w;
  }
  __syncthreads();
#pragma unroll
  for (int p = 0; p < 4; ++p) {
    int idx = tid + p * 256;
    int n = idx >> 4;
    int k4 = idx & 15;
    half4 h;
    h[0] = (_Float16)t[k4 * 4 + 0][n]; h[1] = (_Float16)t[k4 * 4 + 1][n];
    h[2] = (_Float16)t[k4 * 4 + 2][n]; h[3] = (_Float16)t[k4 * 4 + 3][n];
    *(half4*)(WT + (size_t)(row_off + n0 + n) * KD + k0 + k4 * 4) = h;
  }
}

// ---------------- prep: V [bh][s][d] -> V^T [bh][d][s] ----------------
__global__ __launch_bounds__(256) void transpose_v_kernel(const _Float16* __restrict__ vhp,
                                                          _Float16* __restrict__ vtp) {
  __shared__ _Float16 t[64][72];
  int bh = blockIdx.y;           // 0..7  (b*HK+hk)
  int s0 = blockIdx.x * 64;      // 32 tiles over SEQ
  const _Float16* src = vhp + ((size_t)bh * SEQ + s0) * DH;
  _Float16* dst = vtp + (size_t)bh * DH * SEQ + s0;
  int tid = threadIdx.x;
#pragma unroll
  for (int p = 0; p < 2; ++p) {
    int idx = tid + p * 256;     // 512 half8s
    int r = idx >> 3, c8 = idx & 7;
    half8 v = *(const half8*)(src + (size_t)r * DH + c8 * 8);
#pragma unroll
    for (int i = 0; i < 8; ++i) t[r][c8 * 8 + i] = v[i];
  }
  __syncthreads();
#pragma unroll
  for (int p = 0; p < 2; ++p) {
    int idx = tid + p * 256;
    int d = idx >> 3, c8 = idx & 7;
    half8 v;
#pragma unroll
    for (int i = 0; i < 8; ++i) v[i] = t[c8 * 8 + i][d];
    *(half8*)(dst + (size_t)d * SEQ + c8 * 8) = v;
  }
}

// swizzle: XOR bits 4-6 of the byte offset with row&7 (row stride 128B tiles)
#define SWZ(r, kb) ((kb) ^ (((r) & 7) << 4))

// ---------------- K1: fused QKV GEMM + RoPE (table-driven) ----------------
// C[4096][1536] = xh[4096][1024] @ W; cols 0-1023 -> q, 1024-1279 -> k, 1280-1535 -> v
__global__ __launch_bounds__(256) void gemm_qkv_rope(
    const _Float16* __restrict__ xh, const _Float16* __restrict__ WT,
    const float2* __restrict__ rtab,
    _Float16* __restrict__ qh, _Float16* __restrict__ kh, _Float16* __restrict__ vh) {
  __shared__ char As[128 * 64 * 2];
  __shared__ char Bs[128 * 64 * 2];
  int tid = threadIdx.x, lane = tid & 63, wid = tid >> 6;
  int wr = wid >> 1, wc = wid & 1;
  int bm = blockIdx.x, bn = blockIdx.y;

  const _Float16* Ag = xh + (size_t)bm * 128 * KD;
  const _Float16* Bg = WT + (size_t)bn * 128 * KD;

  f32x4 acc[4][4] = {};

  for (int kt = 0; kt < KD / 64; ++kt) {
#pragma unroll
    for (int p = 0; p < 4; ++p) {
      int idx = tid + p * 256;
      int r = idx >> 3, k8 = idx & 7;
      half8 va = *(const half8*)(Ag + (size_t)r * KD + kt * 64 + k8 * 8);
      *(half8*)(As + r * 128 + SWZ(r, k8 * 16)) = va;
      half8 vb = *(const half8*)(Bg + (size_t)r * KD + kt * 64 + k8 * 8);
      *(half8*)(Bs + r * 128 + SWZ(r, k8 * 16)) = vb;
    }
    __syncthreads();
#pragma unroll
    for (int kk = 0; kk < 2; ++kk) {
      int kb = kk * 64 + (lane >> 4) * 16;
      half8 af[4], bf[4];
#pragma unroll
      for (int mf = 0; mf < 4; ++mf) {
        int r = wr * 64 + mf * 16 + (lane & 15);
        af[mf] = *(const half8*)(As + r * 128 + SWZ(r, kb));
      }
#pragma unroll
      for (int nf = 0; nf < 4; ++nf) {
        int r = wc * 64 + nf * 16 + (lane & 15);
        bf[nf] = *(const half8*)(Bs + r * 128 + SWZ(r, kb));
      }
#pragma unroll
      for (int mf = 0; mf < 4; ++mf)
#pragma unroll
        for (int nf = 0; nf < 4; ++nf)
          acc[mf][nf] = __builtin_amdgcn_mfma_f32_16x16x32_f16(af[mf], bf[nf], acc[mf][nf], 0, 0, 0);
    }
    __syncthreads();
  }

  // epilogue: wave covers 64 contiguous cols = exactly one head
  int col0 = bn * 128 + wc * 64;
  int row_base = bm * 128 + wr * 64;
#pragma unroll
  for (int mf = 0; mf < 4; ++mf) {
#pragma unroll
    for (int j = 0; j < 4; ++j) {
      int row = row_base + mf * 16 + (lane >> 4) * 4 + j;
      int b = row >> 11, s = row & (SEQ - 1);
      if (col0 < 1024) {
        int hq = col0 >> 6;
        size_t base = (((size_t)b * HQ + hq) * SEQ + s) * DH;
#pragma unroll
        for (int nf = 0; nf < 2; ++nf) {
          int d = nf * 16 + (lane & 15);  // 0..31
          float2 scv = rtab[row * 32 + d];
          float x1 = acc[mf][nf][j], x2 = acc[mf][nf + 2][j];
          qh[base + d]      = (_Float16)(x1 * scv.y - x2 * scv.x);
          qh[base + d + 32] = (_Float16)(x2 * scv.y + x1 * scv.x);
        }
      } else if (col0 < 1280) {
        int hk = (col0 - 1024) >> 6;
        size_t base = (((size_t)b * HK + hk) * SEQ + s) * DH;
#pragma unroll
        for (int nf = 0; nf < 2; ++nf) {
          int d = nf * 16 + (lane & 15);
          float2 scv = rtab[row * 32 + d];
          float x1 = acc[mf][nf][j], x2 = acc[mf][nf + 2][j];
          kh[base + d]      = (_Float16)(x1 * scv.y - x2 * scv.x);
          kh[base + d + 32] = (_Float16)(x2 * scv.y + x1 * scv.x);
        }
      } else {
        int hk = (col0 - 1280) >> 6;
        size_t base = (((size_t)b * HK + hk) * SEQ + s) * DH;
#pragma unroll
        for (int nf = 0; nf < 4; ++nf) {
          int d = nf * 16 + (lane & 15);
          vh[base + d] = (_Float16)acc[mf][nf][j];
        }
      }
    }
  }
}

// ---------------- K2: flash attention (scale=1.0) ----------------
// grid: (qt=16, bh=32). block 256 = 4 waves x 32 q-rows. KV tile = 128.
// V is pre-transposed in HBM: vt[bh][d][s].
__global__ __launch_bounds__(256) void attn_kernel(
    const _Float16* __restrict__ qh, const _Float16* __restrict__ kh,
    const _Float16* __restrict__ vt, _Float16* __restrict__ oh) {
  __shared__ char Ks[128 * 64 * 2];      // [kv][d] swz, row 128B
  __shared__ char Vs[64 * 128 * 2];      // [d][kv] swz, row 256B
  __shared__ char Ps[4 * 32 * 64 * 2];   // per-wave [32 q][64 kv] swz, row 128B

  int tid = threadIdx.x, lane = tid & 63, wid = tid >> 6;
  int qt = blockIdx.x;
  int bh = blockIdx.y;
  int b = bh >> 4, hq = bh & 15, hk = hq >> 2;

  const _Float16* Qg = qh + (((size_t)b * HQ + hq) * SEQ + qt * 128 + wid * 32) * DH;
  const _Float16* Kg = kh + (((size_t)b * HK + hk) * SEQ) * DH;
  const _Float16* Vtg = vt + (size_t)(b * HK + hk) * DH * SEQ;

  // Q fragments held in registers for the whole block
  half8 qf[2][2];
#pragma unroll
  for (int mf = 0; mf < 2; ++mf)
#pragma unroll
    for (int kk = 0; kk < 2; ++kk)
      qf[mf][kk] = *(const half8*)(Qg + (mf * 16 + (lane & 15)) * DH + kk * 32 + (lane >> 4) * 8);

  f32x4 oacc[2][4] = {};
  float mrow[2][4], lrow[2][4];
#pragma unroll
  for (int mf = 0; mf < 2; ++mf)
#pragma unroll
    for (int j = 0; j < 4; ++j) { mrow[mf][j] = -3e38f; lrow[mf][j] = 0.f; }

  char* Pw = Ps + wid * (32 * 64 * 2);

  for (int kt = 0; kt < SEQ / 128; ++kt) {
    // stage K [128 kv][64 d] and V^T [64 d][128 kv], both vectorized + swz
#pragma unroll
    for (int p = 0; p < 4; ++p) {
      int idx = tid + p * 256;
      int r = idx >> 3, d8 = idx & 7;
      half8 vk = *(const half8*)(Kg + ((size_t)kt * 128 + r) * DH + d8 * 8);
      *(half8*)(Ks + r * 128 + SWZ(r, d8 * 16)) = vk;
    }
#pragma unroll
    for (int p = 0; p < 4; ++p) {
      int idx = tid + p * 256;
      int r = idx >> 4, c8 = idx & 15;   // r = d row, c8 = 16B chunk over kv
      half8 vv = *(const half8*)(Vtg + (size_t)r * SEQ + kt * 128 + c8 * 8);
      *(half8*)(Vs + r * 256 + SWZ(r, c8 * 16)) = vv;
    }
    __syncthreads();

    // scores S[32 q][128 kv] = Q K^T
    f32x4 sc[2][8] = {};
#pragma unroll
    for (int nf = 0; nf < 8; ++nf) {
      int r = nf * 16 + (lane & 15);
      half8 kf0 = *(const half8*)(Ks + r * 128 + SWZ(r, (lane >> 4) * 16));
      half8 kf1 = *(const half8*)(Ks + r * 128 + SWZ(r, (lane >> 4) * 16 + 64));
#pragma unroll
      for (int mf = 0; mf < 2; ++mf) {
        sc[mf][nf] = __builtin_amdgcn_mfma_f32_16x16x32_f16(qf[mf][0], kf0, sc[mf][nf], 0, 0, 0);
        sc[mf][nf] = __builtin_amdgcn_mfma_f32_16x16x32_f16(qf[mf][1], kf1, sc[mf][nf], 0, 0, 0);
      }
    }

    // online softmax (rows split across 16-lane groups; reduce over lane&15)
#pragma unroll
    for (int mf = 0; mf < 2; ++mf) {
#pragma unroll
      for (int j = 0; j < 4; ++j) {
        float pm = sc[mf][0][j];
#pragma unroll
        for (int nf = 1; nf < 8; ++nf) pm = fmaxf(pm, sc[mf][nf][j]);
        pm = fmaxf(pm, __shfl_xor(pm, 1, 64));
        pm = fmaxf(pm, __shfl_xor(pm, 2, 64));
        pm = fmaxf(pm, __shfl_xor(pm, 4, 64));
        pm = fmaxf(pm, __shfl_xor(pm, 8, 64));
        float mnew = fmaxf(mrow[mf][j], pm);
        float alpha = __expf(mrow[mf][j] - mnew);
        mrow[mf][j] = mnew;
        float psum = 0.f;
#pragma unroll
        for (int nf = 0; nf < 8; ++nf) {
          float pv = __expf(sc[mf][nf][j] - mnew);
          sc[mf][nf][j] = pv;
          psum += pv;
        }
        psum += __shfl_xor(psum, 1, 64);
        psum += __shfl_xor(psum, 2, 64);
        psum += __shfl_xor(psum, 4, 64);
        psum += __shfl_xor(psum, 8, 64);
        lrow[mf][j] = lrow[mf][j] * alpha + psum;
#pragma unroll
        for (int nf2 = 0; nf2 < 4; ++nf2) oacc[mf][nf2][j] *= alpha;
      }
    }

    // PV: P via per-wave LDS roundtrip, two kv-halves of 64 (reuses Pw; DS ops
    // from one wave execute in program order so h=1 writes can't pass h=0 reads)
#pragma unroll
    for (int h = 0; h < 2; ++h) {
#pragma unroll
      for (int mf = 0; mf < 2; ++mf)
#pragma unroll
        for (int nfl = 0; nfl < 4; ++nfl)
#pragma unroll
          for (int j = 0; j < 4; ++j) {
            int r = mf * 16 + (lane >> 4) * 4 + j;
            int c = nfl * 16 + (lane & 15);
            *(_Float16*)(Pw + r * 128 + SWZ(r, c * 2)) = (_Float16)sc[mf][h * 4 + nfl][j];
          }
#pragma unroll
      for (int kf = 0; kf < 2; ++kf) {
        int kb = kf * 64 + (lane >> 4) * 16;
        half8 pa[2], vb[4];
#pragma unroll
        for (int mf = 0; mf < 2; ++mf) {
          int r = mf * 16 + (lane & 15);
          pa[mf] = *(const half8*)(Pw + r * 128 + SWZ(r, kb));
        }
        int kvb = (h * 2 + kf) * 64 + (lane >> 4) * 16;
#pragma unroll
        for (int nf2 = 0; nf2 < 4; ++nf2) {
          int dd = nf2 * 16 + (lane & 15);
          vb[nf2] = *(const half8*)(Vs + dd * 256 + SWZ(dd, kvb));
        }
#pragma unroll
        for (int mf = 0; mf < 2; ++mf)
#pragma unroll
          for (int nf2 = 0; nf2 < 4; ++nf2)
            oacc[mf][nf2] = __builtin_amdgcn_mfma_f32_16x16x32_f16(pa[mf], vb[nf2], oacc[mf][nf2], 0, 0, 0);
      }
    }
    __syncthreads();
  }

  // normalize + write [B][S][HQ*DH]
  int s0 = qt * 128 + wid * 32;
#pragma unroll
  for (int mf = 0; mf < 2; ++mf) {
#pragma unroll
    for (int j = 0; j < 4; ++j) {
      int s = s0 + mf * 16 + (lane >> 4) * 4 + j;
      float invl = 1.f / lrow[mf][j];
      size_t base = ((size_t)b * SEQ + s) * 1024 + hq * 64;
#pragma unroll
      for (int nf2 = 0; nf2 < 4; ++nf2) {
        int dd = nf2 * 16 + (lane & 15);
        oh[base + dd] = (_Float16)(oacc[mf][nf2][j] * invl);
      }
    }
  }
}

// ---------------- K3: output projection, fp32 out ----------------
__global__ __launch_bounds__(256) void gemm_out(
    const _Float16* __restrict__ ah, const _Float16* __restrict__ WoT,
    float* __restrict__ out) {
  __shared__ char As[128 * 64 * 2];
  __shared__ char Bs[128 * 64 * 2];
  int tid = threadIdx.x, lane = tid & 63, wid = tid >> 6;
  int wr = wid >> 1, wc = wid & 1;
  int bm = blockIdx.x, bn = blockIdx.y;
  const _Float16* Ag = ah + (size_t)bm * 128 * KD;
  const _Float16* Bg = WoT + (size_t)bn * 128 * KD;
  f32x4 acc[4][4] = {};

  for (int kt = 0; kt < KD / 64; ++kt) {
#pragma unroll
    for (int p = 0; p < 4; ++p) {
      int idx = tid + p * 256;
      int r = idx >> 3, k8 = idx & 7;
      half8 va = *(const half8*)(Ag + (size_t)r * KD + kt * 64 + k8 * 8);
      *(half8*)(As + r * 128 + SWZ(r, k8 * 16)) = va;
      half8 vb = *(const half8*)(Bg + (size_t)r * KD + kt * 64 + k8 * 8);
      *(half8*)(Bs + r * 128 + SWZ(r, k8 * 16)) = vb;
    }
    __syncthreads();
#pragma unroll
    for (int kk = 0; kk < 2; ++kk) {
      int kb = kk * 64 + (lane >> 4) * 16;
      half8 af[4], bf[4];
#pragma unroll
      for (int mf = 0; mf < 4; ++mf) {
        int r = wr * 64 + mf * 16 + (lane & 15);
        af[mf] = *(const half8*)(As + r * 128 + SWZ(r, kb));
      }
#pragma unroll
      for (int nf = 0; nf < 4; ++nf) {
        int r = wc * 64 + nf * 16 + (lane & 15);
        bf[nf] = *(const half8*)(Bs + r * 128 + SWZ(r, kb));
      }
#pragma unroll
      for (int mf = 0; mf < 4; ++mf)
#pragma unroll
        for (int nf = 0; nf < 4; ++nf)
          acc[mf][nf] = __builtin_amdgcn_mfma_f32_16x16x32_f16(af[mf], bf[nf], acc[mf][nf], 0, 0, 0);
    }
    __syncthreads();
  }

  int row0 = bm * 128 + wr * 64, col0 = bn * 128 + wc * 64;
#pragma unroll
  for (int mf = 0; mf < 4; ++mf)
#pragma unroll
    for (int j = 0; j < 4; ++j) {
      int row = row0 + mf * 16 + (lane >> 4) * 4 + j;
#pragma unroll
      for (int nf = 0; nf < 4; ++nf)
        out[(size_t)row * 1024 + col0 + nf * 16 + (lane & 15)] = acc[mf][nf][j];
    }
}

// ---------------- launch ----------------
extern "C" void kernel_launch(void* const* d_in, const int* in_sizes, int n_in,
                              void* d_out, int out_size, void* d_ws, size_t ws_size,
                              hipStream_t stream) {
  const float* x  = (const float*)d_in[0];
  const int* qpos = (const int*)d_in[1];
  const float* Wq = (const float*)d_in[2];
  const float* Wk = (const float*)d_in[3];
  const float* Wv = (const float*)d_in[4];
  const float* Wo = (const float*)d_in[5];
  float* out = (float*)d_out;

  char* ws = (char*)d_ws;
  _Float16* xh  = (_Float16*)(ws);                 // 8 MB  [4096][1024]
  _Float16* WT  = (_Float16*)(ws + 8388608);       // 3 MB  [1536][1024] (q,k,v stacked)
  _Float16* WoT = (_Float16*)(ws + 11534336);      // 2 MB  [1024][1024]
  _Float16* qhp = (_Float16*)(ws + 13631488);      // 8 MB  [B][HQ][S][D]
  _Float16* khp = (_Float16*)(ws + 22020096);      // 2 MB  [B][HK][S][D]
  _Float16* vhp = (_Float16*)(ws + 24117248);      // 2 MB  [B][HK][S][D]
  _Float16* ohp = (_Float16*)(ws + 26214400);      // 8 MB  [4096][1024]
  float2*   rtab = (float2*)(ws + 34603008);       // 1 MB  [4096][32]
  _Float16* vtp = (_Float16*)(ws + 35651584);      // 2 MB  [B][HK][D][S]

  cvt_x_kernel<<<4096, 256, 0, stream>>>(x, xh, 1048576);
  rope_tab_kernel<<<512, 256, 0, stream>>>(qpos, rtab);
  transpose_w_kernel<<<dim3(16, 16), 256, 0, stream>>>(Wq, WT, 1024, 0);
  transpose_w_kernel<<<dim3(4, 16), 256, 0, stream>>>(Wk, WT, 256, 1024);
  transpose_w_kernel<<<dim3(4, 16), 256, 0, stream>>>(Wv, WT, 256, 1280);
  transpose_w_kernel<<<dim3(16, 16), 256, 0, stream>>>(Wo, WoT, 1024, 0);
  gemm_qkv_rope<<<dim3(32, 12), 256, 0, stream>>>(xh, WT, rtab, qhp, khp, vhp);
  transpose_v_kernel<<<dim3(32, 8), 256, 0, stream>>>(vhp, vtp);
  attn_kernel<<<dim3(16, 32), 256, 0, stream>>>(qhp, khp, vtp, ohp);
  gemm_out<<<dim3(32, 8), 256, 0, stream>>>(ohp, WoT, out);
}

// Round 5
// 147.014 us; speedup vs baseline: 2.7838x; 1.2895x over previous
//
#include <hip/hip_runtime.h>
#include <hip/hip_fp16.h>
#include <math.h>

typedef __attribute__((ext_vector_type(8))) _Float16 half8;
typedef __attribute__((ext_vector_type(4))) _Float16 half4;
typedef __attribute__((ext_vector_type(4))) float f32x4;

#define HQ 16
#define HK 4
#define DH 64
#define NB 2
#define SEQ 2048
#define EDIM 1024
#define KD 1024

// ---------------- prep: convert x to f16 ----------------
__global__ __launch_bounds__(256) void cvt_x_kernel(const float* __restrict__ x,
                                                    _Float16* __restrict__ xh, int n4) {
  int i = blockIdx.x * 256 + threadIdx.x;
  if (i >= n4) return;
  float4 v = ((const float4*)x)[i];
  half4 h;
  h[0] = (_Float16)v.x; h[1] = (_Float16)v.y; h[2] = (_Float16)v.z; h[3] = (_Float16)v.w;
  *(half4*)(xh + (size_t)i * 4) = h;
}

// ---------------- prep: RoPE sin/cos table [4096 rows][32 freqs] ----------------
__global__ __launch_bounds__(256) void rope_tab_kernel(const int* __restrict__ qpos,
                                                       float2* __restrict__ tab) {
  int i = blockIdx.x * 256 + threadIdx.x;   // 0 .. 4096*32-1
  int row = i >> 5, d = i & 31;
  float ang = (float)qpos[row] * expf((float)d * -0.2878231366242558f); // -ln(10000)/32
  float sn, cs;
  sincosf(ang, &sn, &cs);
  tab[i] = make_float2(sn, cs);
}

// ---------------- prep: W [K][N] f32 -> WT [N][K] f16 ----------------
__global__ __launch_bounds__(256) void transpose_w_kernel(const float* __restrict__ W,
                                                          _Float16* __restrict__ WT,
                                                          int N, int row_off) {
  __shared__ float t[64][65];
  int n0 = blockIdx.x * 64, k0 = blockIdx.y * 64;
  int tid = threadIdx.x;
#pragma unroll
  for (int p = 0; p < 4; ++p) {
    int idx = tid + p * 256;
    int r = idx >> 4;      // k row 0..63
    int c4 = idx & 15;     // float4 col
    float4 v = *(const float4*)(W + (size_t)(k0 + r) * N + n0 + c4 * 4);
    t[r][c4 * 4 + 0] = v.x; t[r][c4 * 4 + 1] = v.y;
    t[r][c4 * 4 + 2] = v.z; t[r][c4 * 4 + 3] = v.w;
  }
  __syncthreads();
#pragma unroll
  for (int p = 0; p < 4; ++p) {
    int idx = tid + p * 256;
    int n = idx >> 4;
    int k4 = idx & 15;
    half4 h;
    h[0] = (_Float16)t[k4 * 4 + 0][n]; h[1] = (_Float16)t[k4 * 4 + 1][n];
    h[2] = (_Float16)t[k4 * 4 + 2][n]; h[3] = (_Float16)t[k4 * 4 + 3][n];
    *(half4*)(WT + (size_t)(row_off + n0 + n) * KD + k0 + k4 * 4) = h;
  }
}

// ---------------- prep: V [bh][s][d] -> V^T [bh][d][s] ----------------
__global__ __launch_bounds__(256) void transpose_v_kernel(const _Float16* __restrict__ vhp,
                                                          _Float16* __restrict__ vtp) {
  __shared__ _Float16 t[64][72];
  int bh = blockIdx.y;           // 0..7  (b*HK+hk)
  int s0 = blockIdx.x * 64;      // 32 tiles over SEQ
  const _Float16* src = vhp + ((size_t)bh * SEQ + s0) * DH;
  _Float16* dst = vtp + (size_t)bh * DH * SEQ + s0;
  int tid = threadIdx.x;
#pragma unroll
  for (int p = 0; p < 2; ++p) {
    int idx = tid + p * 256;     // 512 half8s
    int r = idx >> 3, c8 = idx & 7;
    half8 v = *(const half8*)(src + (size_t)r * DH + c8 * 8);
#pragma unroll
    for (int i = 0; i < 8; ++i) t[r][c8 * 8 + i] = v[i];
  }
  __syncthreads();
#pragma unroll
  for (int p = 0; p < 2; ++p) {
    int idx = tid + p * 256;
    int d = idx >> 3, c8 = idx & 7;
    half8 v;
#pragma unroll
    for (int i = 0; i < 8; ++i) v[i] = t[c8 * 8 + i][d];
    *(half8*)(dst + (size_t)d * SEQ + c8 * 8) = v;
  }
}

// swizzle: XOR bits 4-6 of the byte offset with row&7 (row stride 128B tiles)
#define SWZ(r, kb) ((kb) ^ (((r) & 7) << 4))

// ---------------- K1: fused QKV GEMM + RoPE (table-driven) ----------------
// C[4096][1536] = xh[4096][1024] @ W; cols 0-1023 -> q, 1024-1279 -> k, 1280-1535 -> v
__global__ __launch_bounds__(256) void gemm_qkv_rope(
    const _Float16* __restrict__ xh, const _Float16* __restrict__ WT,
    const float2* __restrict__ rtab,
    _Float16* __restrict__ qh, _Float16* __restrict__ kh, _Float16* __restrict__ vh) {
  __shared__ char As[128 * 64 * 2];
  __shared__ char Bs[128 * 64 * 2];
  int tid = threadIdx.x, lane = tid & 63, wid = tid >> 6;
  int wr = wid >> 1, wc = wid & 1;
  int bm = blockIdx.x, bn = blockIdx.y;

  const _Float16* Ag = xh + (size_t)bm * 128 * KD;
  const _Float16* Bg = WT + (size_t)bn * 128 * KD;

  f32x4 acc[4][4] = {};

  for (int kt = 0; kt < KD / 64; ++kt) {
#pragma unroll
    for (int p = 0; p < 4; ++p) {
      int idx = tid + p * 256;
      int r = idx >> 3, k8 = idx & 7;
      half8 va = *(const half8*)(Ag + (size_t)r * KD + kt * 64 + k8 * 8);
      *(half8*)(As + r * 128 + SWZ(r, k8 * 16)) = va;
      half8 vb = *(const half8*)(Bg + (size_t)r * KD + kt * 64 + k8 * 8);
      *(half8*)(Bs + r * 128 + SWZ(r, k8 * 16)) = vb;
    }
    __syncthreads();
#pragma unroll
    for (int kk = 0; kk < 2; ++kk) {
      int kb = kk * 64 + (lane >> 4) * 16;
      half8 af[4], bf[4];
#pragma unroll
      for (int mf = 0; mf < 4; ++mf) {
        int r = wr * 64 + mf * 16 + (lane & 15);
        af[mf] = *(const half8*)(As + r * 128 + SWZ(r, kb));
      }
#pragma unroll
      for (int nf = 0; nf < 4; ++nf) {
        int r = wc * 64 + nf * 16 + (lane & 15);
        bf[nf] = *(const half8*)(Bs + r * 128 + SWZ(r, kb));
      }
#pragma unroll
      for (int mf = 0; mf < 4; ++mf)
#pragma unroll
        for (int nf = 0; nf < 4; ++nf)
          acc[mf][nf] = __builtin_amdgcn_mfma_f32_16x16x32_f16(af[mf], bf[nf], acc[mf][nf], 0, 0, 0);
    }
    __syncthreads();
  }

  // epilogue: wave covers 64 contiguous cols = exactly one head
  int col0 = bn * 128 + wc * 64;
  int row_base = bm * 128 + wr * 64;
#pragma unroll
  for (int mf = 0; mf < 4; ++mf) {
#pragma unroll
    for (int j = 0; j < 4; ++j) {
      int row = row_base + mf * 16 + (lane >> 4) * 4 + j;
      int b = row >> 11, s = row & (SEQ - 1);
      if (col0 < 1024) {
        int hq = col0 >> 6;
        size_t base = (((size_t)b * HQ + hq) * SEQ + s) * DH;
#pragma unroll
        for (int nf = 0; nf < 2; ++nf) {
          int d = nf * 16 + (lane & 15);  // 0..31
          float2 scv = rtab[row * 32 + d];
          float x1 = acc[mf][nf][j], x2 = acc[mf][nf + 2][j];
          qh[base + d]      = (_Float16)(x1 * scv.y - x2 * scv.x);
          qh[base + d + 32] = (_Float16)(x2 * scv.y + x1 * scv.x);
        }
      } else if (col0 < 1280) {
        int hk = (col0 - 1024) >> 6;
        size_t base = (((size_t)b * HK + hk) * SEQ + s) * DH;
#pragma unroll
        for (int nf = 0; nf < 2; ++nf) {
          int d = nf * 16 + (lane & 15);
          float2 scv = rtab[row * 32 + d];
          float x1 = acc[mf][nf][j], x2 = acc[mf][nf + 2][j];
          kh[base + d]      = (_Float16)(x1 * scv.y - x2 * scv.x);
          kh[base + d + 32] = (_Float16)(x2 * scv.y + x1 * scv.x);
        }
      } else {
        int hk = (col0 - 1280) >> 6;
        size_t base = (((size_t)b * HK + hk) * SEQ + s) * DH;
#pragma unroll
        for (int nf = 0; nf < 4; ++nf) {
          int d = nf * 16 + (lane & 15);
          vh[base + d] = (_Float16)acc[mf][nf][j];
        }
      }
    }
  }
}

// ---------------- K2: flash attention, swapped-QK^T (S^T), scale=1.0 ----------------
// grid: (qt=16, bh=32). block 256 = 4 waves x 32 q-rows. KV tile = 128.
// V is pre-transposed in HBM: vt[bh][d][s]. Q pre-scaled by log2e; exp -> exp2.
__global__ __launch_bounds__(256) void attn_kernel(
    const _Float16* __restrict__ qh, const _Float16* __restrict__ kh,
    const _Float16* __restrict__ vt, _Float16* __restrict__ oh) {
  __shared__ char Ks[128 * 64 * 2];       // [kv][d] swz, row 128B
  __shared__ char Vs[64 * 128 * 2];       // [d][kv] swz, row 256B
  __shared__ char Ps[4 * 32 * 128 * 2];   // per-wave [32 q][128 kv] swz, row 256B

  int tid = threadIdx.x, lane = tid & 63, wid = tid >> 6;
  int g = lane >> 4, qi = lane & 15;
  int qt = blockIdx.x;
  int bh = blockIdx.y;
  int b = bh >> 4, hq = bh & 15, hk = hq >> 2;

  const _Float16* Qg = qh + (((size_t)b * HQ + hq) * SEQ + qt * 128 + wid * 32) * DH;
  const _Float16* Kg = kh + (((size_t)b * HK + hk) * SEQ) * DH;
  const _Float16* Vtg = vt + (size_t)(b * HK + hk) * DH * SEQ;

  // Q fragments in registers, pre-scaled by log2(e) so softmax uses exp2
  const _Float16 l2e = (_Float16)1.44269504f;
  half8 qf[2][2];
#pragma unroll
  for (int mf = 0; mf < 2; ++mf)
#pragma unroll
    for (int kk = 0; kk < 2; ++kk) {
      half8 q0 = *(const half8*)(Qg + (mf * 16 + qi) * DH + kk * 32 + g * 8);
#pragma unroll
      for (int i = 0; i < 8; ++i) q0[i] = q0[i] * l2e;
      qf[mf][kk] = q0;
    }

  f32x4 oacc[2][4] = {};          // O^T: [q-block mf][d-block nf2], lane: d=nf2*16+g*4+j, q=mf*16+qi
  float mrow[2] = {-3e38f, -3e38f};
  float lrow[2] = {0.f, 0.f};

  char* Pw = Ps + wid * (32 * 128 * 2);

  for (int kt = 0; kt < SEQ / 128; ++kt) {
    // stage K [128 kv][64 d] and V^T [64 d][128 kv], vectorized + swz
#pragma unroll
    for (int p = 0; p < 4; ++p) {
      int idx = tid + p * 256;
      int r = idx >> 3, d8 = idx & 7;
      half8 vk = *(const half8*)(Kg + ((size_t)kt * 128 + r) * DH + d8 * 8);
      *(half8*)(Ks + r * 128 + SWZ(r, d8 * 16)) = vk;
    }
#pragma unroll
    for (int p = 0; p < 4; ++p) {
      int idx = tid + p * 256;
      int r = idx >> 4, c8 = idx & 15;   // r = d row, c8 = 16B chunk over kv
      half8 vv = *(const half8*)(Vtg + (size_t)r * SEQ + kt * 128 + c8 * 8);
      *(half8*)(Vs + r * 256 + SWZ(r, c8 * 16)) = vv;
    }
    __syncthreads();

    // S^T[128 kv][32 q] = K Q^T : lane holds S[q=mf*16+qi][kv=nf*16+g*4+j]
    f32x4 sc[2][8] = {};
#pragma unroll
    for (int nf = 0; nf < 8; ++nf) {
      int r = nf * 16 + qi;
      half8 kf0 = *(const half8*)(Ks + r * 128 + SWZ(r, g * 16));
      half8 kf1 = *(const half8*)(Ks + r * 128 + SWZ(r, g * 16 + 64));
#pragma unroll
      for (int mf = 0; mf < 2; ++mf) {
        sc[mf][nf] = __builtin_amdgcn_mfma_f32_16x16x32_f16(kf0, qf[mf][0], sc[mf][nf], 0, 0, 0);
        sc[mf][nf] = __builtin_amdgcn_mfma_f32_16x16x32_f16(kf1, qf[mf][1], sc[mf][nf], 0, 0, 0);
      }
    }

    // online softmax: row q is lane-local (32 vals) + 4-group combine (xor 16,32)
#pragma unroll
    for (int mf = 0; mf < 2; ++mf) {
      float p0 = sc[mf][0][0], p1 = sc[mf][0][1], p2 = sc[mf][0][2], p3 = sc[mf][0][3];
#pragma unroll
      for (int nf = 1; nf < 8; ++nf) {
        p0 = fmaxf(p0, sc[mf][nf][0]); p1 = fmaxf(p1, sc[mf][nf][1]);
        p2 = fmaxf(p2, sc[mf][nf][2]); p3 = fmaxf(p3, sc[mf][nf][3]);
      }
      float pm = fmaxf(fmaxf(p0, p1), fmaxf(p2, p3));
      pm = fmaxf(pm, __shfl_xor(pm, 16, 64));
      pm = fmaxf(pm, __shfl_xor(pm, 32, 64));
      float mnew = fmaxf(mrow[mf], pm);
      float alpha = __builtin_amdgcn_exp2f(mrow[mf] - mnew);
      mrow[mf] = mnew;
      float s0 = 0.f, s1 = 0.f, s2 = 0.f, s3 = 0.f;
      int prow = mf * 16 + qi;
      char* pwr = Pw + prow * 256;
      int pswz = (prow & 7) << 4;
#pragma unroll
      for (int nf = 0; nf < 8; ++nf) {
        float e0 = __builtin_amdgcn_exp2f(sc[mf][nf][0] - mnew);
        float e1 = __builtin_amdgcn_exp2f(sc[mf][nf][1] - mnew);
        float e2 = __builtin_amdgcn_exp2f(sc[mf][nf][2] - mnew);
        float e3 = __builtin_amdgcn_exp2f(sc[mf][nf][3] - mnew);
        s0 += e0; s1 += e1; s2 += e2; s3 += e3;
        uint2 w;
        w.x = __builtin_bit_cast(unsigned, __builtin_amdgcn_cvt_pkrtz(e0, e1));
        w.y = __builtin_bit_cast(unsigned, __builtin_amdgcn_cvt_pkrtz(e2, e3));
        *(uint2*)(pwr + ((nf * 32 + g * 8) ^ pswz)) = w;   // one ds_write_b64
      }
      float psum = (s0 + s1) + (s2 + s3);
      psum += __shfl_xor(psum, 16, 64);
      psum += __shfl_xor(psum, 32, 64);
      lrow[mf] = lrow[mf] * alpha + psum;
#pragma unroll
      for (int nf2 = 0; nf2 < 4; ++nf2)
#pragma unroll
        for (int j = 0; j < 4; ++j) oacc[mf][nf2][j] *= alpha;
    }

    // PV: O^T += V^T (A) x P^T (B), 4 k-blocks of 32 kv
#pragma unroll
    for (int t = 0; t < 4; ++t) {
      half8 pb[2], vb[4];
#pragma unroll
      for (int mf = 0; mf < 2; ++mf) {
        int r = mf * 16 + qi;
        pb[mf] = *(const half8*)(Pw + r * 256 + SWZ(r, t * 64 + g * 16));
      }
#pragma unroll
      for (int nf2 = 0; nf2 < 4; ++nf2) {
        int dd = nf2 * 16 + qi;
        vb[nf2] = *(const half8*)(Vs + dd * 256 + SWZ(dd, t * 64 + g * 16));
      }
#pragma unroll
      for (int mf = 0; mf < 2; ++mf)
#pragma unroll
        for (int nf2 = 0; nf2 < 4; ++nf2)
          oacc[mf][nf2] = __builtin_amdgcn_mfma_f32_16x16x32_f16(vb[nf2], pb[mf], oacc[mf][nf2], 0, 0, 0);
    }
    __syncthreads();
  }

  // normalize + write [B][S][HQ*DH]; lane's q is fixed per mf, d = nf2*16+g*4+j
#pragma unroll
  for (int mf = 0; mf < 2; ++mf) {
    int s = qt * 128 + wid * 32 + mf * 16 + qi;
    float invl = 1.f / lrow[mf];
    size_t base = ((size_t)b * SEQ + s) * 1024 + hq * 64;
#pragma unroll
    for (int nf2 = 0; nf2 < 4; ++nf2) {
      half4 o;
#pragma unroll
      for (int j = 0; j < 4; ++j) o[j] = (_Float16)(oacc[mf][nf2][j] * invl);
      *(half4*)(oh + base + nf2 * 16 + g * 4) = o;
    }
  }
}

// ---------------- K3: output projection, fp32 out ----------------
__global__ __launch_bounds__(256) void gemm_out(
    const _Float16* __restrict__ ah, const _Float16* __restrict__ WoT,
    float* __restrict__ out) {
  __shared__ char As[128 * 64 * 2];
  __shared__ char Bs[128 * 64 * 2];
  int tid = threadIdx.x, lane = tid & 63, wid = tid >> 6;
  int wr = wid >> 1, wc = wid & 1;
  int bm = blockIdx.x, bn = blockIdx.y;
  const _Float16* Ag = ah + (size_t)bm * 128 * KD;
  const _Float16* Bg = WoT + (size_t)bn * 128 * KD;
  f32x4 acc[4][4] = {};

  for (int kt = 0; kt < KD / 64; ++kt) {
#pragma unroll
    for (int p = 0; p < 4; ++p) {
      int idx = tid + p * 256;
      int r = idx >> 3, k8 = idx & 7;
      half8 va = *(const half8*)(Ag + (size_t)r * KD + kt * 64 + k8 * 8);
      *(half8*)(As + r * 128 + SWZ(r, k8 * 16)) = va;
      half8 vb = *(const half8*)(Bg + (size_t)r * KD + kt * 64 + k8 * 8);
      *(half8*)(Bs + r * 128 + SWZ(r, k8 * 16)) = vb;
    }
    __syncthreads();
#pragma unroll
    for (int kk = 0; kk < 2; ++kk) {
      int kb = kk * 64 + (lane >> 4) * 16;
      half8 af[4], bf[4];
#pragma unroll
      for (int mf = 0; mf < 4; ++mf) {
        int r = wr * 64 + mf * 16 + (lane & 15);
        af[mf] = *(const half8*)(As + r * 128 + SWZ(r, kb));
      }
#pragma unroll
      for (int nf = 0; nf < 4; ++nf) {
        int r = wc * 64 + nf * 16 + (lane & 15);
        bf[nf] = *(const half8*)(Bs + r * 128 + SWZ(r, kb));
      }
#pragma unroll
      for (int mf = 0; mf < 4; ++mf)
#pragma unroll
        for (int nf = 0; nf < 4; ++nf)
          acc[mf][nf] = __builtin_amdgcn_mfma_f32_16x16x32_f16(af[mf], bf[nf], acc[mf][nf], 0, 0, 0);
    }
    __syncthreads();
  }

  int row0 = bm * 128 + wr * 64, col0 = bn * 128 + wc * 64;
#pragma unroll
  for (int mf = 0; mf < 4; ++mf)
#pragma unroll
    for (int j = 0; j < 4; ++j) {
      int row = row0 + mf * 16 + (lane >> 4) * 4 + j;
#pragma unroll
      for (int nf = 0; nf < 4; ++nf)
        out[(size_t)row * 1024 + col0 + nf * 16 + (lane & 15)] = acc[mf][nf][j];
    }
}

// ---------------- launch ----------------
extern "C" void kernel_launch(void* const* d_in, const int* in_sizes, int n_in,
                              void* d_out, int out_size, void* d_ws, size_t ws_size,
                              hipStream_t stream) {
  const float* x  = (const float*)d_in[0];
  const int* qpos = (const int*)d_in[1];
  const float* Wq = (const float*)d_in[2];
  const float* Wk = (const float*)d_in[3];
  const float* Wv = (const float*)d_in[4];
  const float* Wo = (const float*)d_in[5];
  float* out = (float*)d_out;

  char* ws = (char*)d_ws;
  _Float16* xh  = (_Float16*)(ws);                 // 8 MB  [4096][1024]
  _Float16* WT  = (_Float16*)(ws + 8388608);       // 3 MB  [1536][1024] (q,k,v stacked)
  _Float16* WoT = (_Float16*)(ws + 11534336);      // 2 MB  [1024][1024]
  _Float16* qhp = (_Float16*)(ws + 13631488);      // 8 MB  [B][HQ][S][D]
  _Float16* khp = (_Float16*)(ws + 22020096);      // 2 MB  [B][HK][S][D]
  _Float16* vhp = (_Float16*)(ws + 24117248);      // 2 MB  [B][HK][S][D]
  _Float16* ohp = (_Float16*)(ws + 26214400);      // 8 MB  [4096][1024]
  float2*   rtab = (float2*)(ws + 34603008);       // 1 MB  [4096][32]
  _Float16* vtp = (_Float16*)(ws + 35651584);      // 2 MB  [B][HK][D][S]

  cvt_x_kernel<<<4096, 256, 0, stream>>>(x, xh, 1048576);
  rope_tab_kernel<<<512, 256, 0, stream>>>(qpos, rtab);
  transpose_w_kernel<<<dim3(16, 16), 256, 0, stream>>>(Wq, WT, 1024, 0);
  transpose_w_kernel<<<dim3(4, 16), 256, 0, stream>>>(Wk, WT, 256, 1024);
  transpose_w_kernel<<<dim3(4, 16), 256, 0, stream>>>(Wv, WT, 256, 1280);
  transpose_w_kernel<<<dim3(16, 16), 256, 0, stream>>>(Wo, WoT, 1024, 0);
  gemm_qkv_rope<<<dim3(32, 12), 256, 0, stream>>>(xh, WT, rtab, qhp, khp, vhp);
  transpose_v_kernel<<<dim3(32, 8), 256, 0, stream>>>(vhp, vtp);
  attn_kernel<<<dim3(16, 32), 256, 0, stream>>>(qhp, khp, vtp, ohp);
  gemm_out<<<dim3(32, 8), 256, 0, stream>>>(ohp, WoT, out);
}